// Round 5
// baseline (404.422 us; speedup 1.0000x reference)
//
#include <hip/hip_runtime.h>
#include <hip/hip_bf16.h>

#define DD 768
#define HH 3072
#define BB 64
#define TT 262   // NCLS + P tokens per batch
#define DH (DD * HH)

typedef __bf16 bf16x8 __attribute__((ext_vector_type(8)));
typedef float f32x4 __attribute__((ext_vector_type(4)));
typedef unsigned short u16;
typedef unsigned int u32;

__device__ __constant__ int A_FIRST[12]  = {0,3, 0,4, 1,3, 1,4, 2,3, 2,4};
__device__ __constant__ int A_SECOND[12] = {3,0, 4,0, 3,1, 4,1, 3,2, 4,2};

// tanh-form gelu: max |dev| from exact erf-gelu ~0.003 abs; output tol 0.039 -> safe
__device__ __forceinline__ float gelu_f(float x) {
  float n2t = x * fmaf(x * x, -0.0713548163f, -1.5957691216f);
  return x * __builtin_amdgcn_rcpf(1.0f + __expf(n2t));
}

__device__ __forceinline__ u16 f2bf(float x) {
  u32 u = __builtin_bit_cast(u32, x);
  return (u16)((u + 0x7fffu + ((u >> 16) & 1u)) >> 16);  // RNE
}

__device__ __forceinline__ void load_lds16(const void* g, void* l) {
  __builtin_amdgcn_global_load_lds(
      (const __attribute__((address_space(1))) void*)g,
      (__attribute__((address_space(3))) void*)l,
      16, 0, 0);
}

// =================== weight transpose+cast, 64x64 tiles, vectorized both sides ===========
// mat 0: W1 (768,3072)->W1t; 1-5: A1W; 6: W2 (3072,768)->W2t; 7-11: A2W. 576 tiles each.
// LDS: column-major tileT[c*68 + row] (stride 68 elems = 136 B, 8B-aligned).
__global__ __launch_bounds__(256)
void wtrans(const float* __restrict__ W1, const float* __restrict__ A1W,
            const float* __restrict__ W2, const float* __restrict__ A2W,
            u16* __restrict__ W1t, u16* __restrict__ A1t,
            u16* __restrict__ W2t, u16* __restrict__ A2t) {
  __shared__ u16 tileT[64 * 68];
  const int bx = blockIdx.x, tid = threadIdx.x;
  const int mat = bx / 576, t = bx % 576;
  const float* ip;
  u16* op;
  int R, C;
  if (mat < 6) {
    R = DD; C = HH;
    ip = mat ? A1W + (size_t)(mat - 1) * DH : W1;
    op = mat ? A1t + (size_t)(mat - 1) * DH : W1t;
  } else {
    int z = mat - 6;
    R = HH; C = DD;
    ip = z ? A2W + (size_t)(z - 1) * DH : W2;
    op = z ? A2t + (size_t)(z - 1) * DH : W2t;
  }
  const int ct = C >> 6;
  const int r0 = (t / ct) << 6, c0 = (t % ct) << 6;
  const int rr = tid >> 4;          // 0..15
  const int cg = (tid & 15) << 2;   // 0,4,..,60
#pragma unroll
  for (int it = 0; it < 4; ++it) {
    int row = rr + (it << 4);
    float4 v = *(const float4*)(ip + (size_t)(r0 + row) * C + c0 + cg);
    tileT[(cg + 0) * 68 + row] = f2bf(v.x);
    tileT[(cg + 1) * 68 + row] = f2bf(v.y);
    tileT[(cg + 2) * 68 + row] = f2bf(v.z);
    tileT[(cg + 3) * 68 + row] = f2bf(v.w);
  }
  __syncthreads();
#pragma unroll
  for (int it = 0; it < 2; ++it) {
    int u = (it << 8) + tid;
    int oc = u >> 3, seg = (u & 7) << 3;   // 8 out-elems (16 B)
    const u16* src = tileT + oc * 68 + seg;
    uint2 lo = *(const uint2*)(src);
    uint2 hi = *(const uint2*)(src + 4);
    uint4 val = make_uint4(lo.x, lo.y, hi.x, hi.y);
    *(uint4*)(op + (size_t)(c0 + oc) * R + r0 + seg) = val;
  }
}

// =================== cast x (32B/thread) + gate ===================
// blocks [0,6288): cast (8 elems/thread); [6288,6384): gate (4 waves/block, 384 units)
__global__ __launch_bounds__(256)
void castgate(const float* __restrict__ x, const float* __restrict__ GW,
              u16* __restrict__ xb, int* __restrict__ sel) {
  const int bx = blockIdx.x, tid = threadIdx.x;
  if (bx < 6288) {
    size_t i = ((size_t)bx * 256 + tid) * 2;  // float4 index; 6288*256*2 = 3219456 exact
    float4 v0 = ((const float4*)x)[i];
    float4 v1 = ((const float4*)x)[i + 1];
    union { u16 s[8]; uint4 d; } pk;
    pk.s[0] = f2bf(v0.x); pk.s[1] = f2bf(v0.y); pk.s[2] = f2bf(v0.z); pk.s[3] = f2bf(v0.w);
    pk.s[4] = f2bf(v1.x); pk.s[5] = f2bf(v1.y); pk.s[6] = f2bf(v1.z); pk.s[7] = f2bf(v1.w);
    *(uint4*)(xb + i * 4) = pk.d;
  } else {
    int unit = (bx - 6288) * 4 + (tid >> 6);  // 384 = 64 b x 6 cls
    int lane = tid & 63;
    int b = unit & 63, i = unit >> 6;
    const float* tok = x + (size_t)(b * TT + i) * DD;
    const float* g = GW + (size_t)i * DD * 2;
    float p0 = 0.f, p1 = 0.f;
    for (int k = lane; k < DD; k += 64) {
      float tv = tok[k];
      p0 += tv * g[k * 2 + 0];
      p1 += tv * g[k * 2 + 1];
    }
#pragma unroll
    for (int o = 32; o; o >>= 1) { p0 += __shfl_xor(p0, o); p1 += __shfl_xor(p1, o); }
    if (lane == 0) sel[i * 64 + b] = (p0 > p1) ? 0 : ((p1 > p0) ? 1 : 2);
  }
}

// =================== MFMA GEMM body, BK=64, XOR-swizzled LDS, swapped-operand ===================
// mfma(b_frag, a_frag, acc): lane holds m = r, n = q*4+[0..4) -> packed stores.
// MODE 0: patch layer1: A=xb patches, B=W1t, out=hid bf16 (bias+gelu). 128x256, supertiled.
// MODE 1: patch layer2: A=hid, B=W2t, out=d_out fp32 (bias), row remap. 128x128, supertiled.
// MODE 2: cls layer1  : A=xb cls rows, B=A1t[e], out=hcls bf16 (bias+gelu). 64x128.
// MODE 3: cls layer2  : A=hcls[combo], B=A2t[e], full K, masked+biased write to out. 64x128.
template <int BM, int BN, int MODE>
__device__ __forceinline__
void gemm_body(char* __restrict__ smem, int bx,
               const __hip_bfloat16* __restrict__ A,
               const __hip_bfloat16* __restrict__ Bw,
               const float* __restrict__ bias,
               void* __restrict__ Out,
               const int* __restrict__ sel) {
  constexpr int KDIM = (MODE == 0 || MODE == 2) ? DD : HH;
  constexpr int KITERS = KDIM / 64;
  constexpr int WAVES_M = (BM == 128) ? 2 : 1;
  constexpr int WAVES_N = 4 / WAVES_M;
  constexpr int MT = BM / (16 * WAVES_M);
  constexpr int NT = BN / (16 * WAVES_N);
  constexpr int CHA = BM / 32;
  constexpr int CHB = BN / 32;

  char* As = smem;
  char* Bs = smem + BM * 128;

  const int tid = threadIdx.x;
  const int lane = tid & 63;
  const int wave = tid >> 6;
  const int q = lane >> 4;
  const int r = lane & 15;
  const int wave_m = wave / WAVES_N;
  const int wave_n = wave % WAVES_N;

  int m0 = 0, n0, combo = 0, cls_i = 0;
  const __hip_bfloat16* Bp = Bw;
  const float* biasp = bias;
  if constexpr (MODE == 0) {
    int chunk = bx / 192, local = bx % 192;
    int nb = local / 16, mloc = local % 16;
    m0 = (chunk * 16 + mloc) * BM;
    n0 = nb * BN;
  } else if constexpr (MODE == 1) {
    int chunk = bx / 96, local = bx % 96;
    int nb = local / 16, mloc = local % 16;
    m0 = (chunk * 16 + mloc) * BM;
    n0 = nb * BN;
  } else if constexpr (MODE == 2) {
    n0 = (bx % 24) * BN;
    combo = bx / 24;
    cls_i = combo >> 1;
    int e = A_FIRST[combo];
    Bp = Bw + (size_t)e * DH;
    biasp = bias + e * HH;
  } else {
    n0 = (bx % 6) * BN;
    combo = bx / 6;
    cls_i = combo >> 1;
    int e = A_SECOND[combo];
    Bp = Bw + (size_t)e * DH;
    biasp = bias + e * DD;
  }

  const int trow = tid >> 3;
  const int sw = ((tid & 7) ^ (trow & 7)) << 4;
  size_t a_row_off;
  if constexpr (MODE == 0) {
    int m = m0 + trow;
    a_row_off = (size_t)((m >> 8) * TT + 6 + (m & 255)) * DD * 2;
  } else if constexpr (MODE == 1) {
    a_row_off = (size_t)(m0 + trow) * HH * 2;
  } else if constexpr (MODE == 2) {
    a_row_off = (size_t)(trow * TT + cls_i) * DD * 2;
  } else {
    a_row_off = (size_t)(combo * 64 + trow) * HH * 2;
  }
  const char* gA0 = (const char*)A + a_row_off + sw;
  const char* gB0 = (const char*)Bp + (size_t)(n0 + trow) * KDIM * 2 + sw;
  constexpr size_t ASTR = (size_t)32 * ((MODE == 0) ? DD : (MODE == 2) ? TT * DD : HH) * 2;
  constexpr size_t BSTR = (size_t)32 * KDIM * 2;
  const int wave_base = (tid & ~63) * 16;

  f32x4 acc[MT][NT];
#pragma unroll
  for (int i_ = 0; i_ < MT; ++i_)
#pragma unroll
    for (int j_ = 0; j_ < NT; ++j_) acc[i_][j_] = (f32x4){0.f, 0.f, 0.f, 0.f};

  const char* a_rd = As + (wave_m * (MT * 16) + r) * 128;
  const char* b_rd = Bs + (wave_n * (NT * 16) + r) * 128;
  const int sa = ((q ^ (r & 7)) << 4);

  for (int kt = 0; kt < KITERS; ++kt) {
#pragma unroll
    for (int u = 0; u < CHA; ++u) load_lds16(gA0 + u * ASTR, As + u * 4096 + wave_base);
#pragma unroll
    for (int u = 0; u < CHB; ++u) load_lds16(gB0 + u * BSTR, Bs + u * 4096 + wave_base);
    gA0 += 128;
    gB0 += 128;
    __syncthreads();
#pragma unroll
    for (int t = 0; t < 2; ++t) {
      const int so = sa ^ (t << 6);
      bf16x8 af[MT], bf[NT];
#pragma unroll
      for (int i_ = 0; i_ < MT; ++i_) af[i_] = *(const bf16x8*)(a_rd + i_ * 2048 + so);
#pragma unroll
      for (int j_ = 0; j_ < NT; ++j_) bf[j_] = *(const bf16x8*)(b_rd + j_ * 2048 + so);
#pragma unroll
      for (int i_ = 0; i_ < MT; ++i_)
#pragma unroll
        for (int j_ = 0; j_ < NT; ++j_)
          acc[i_][j_] = __builtin_amdgcn_mfma_f32_16x16x32_bf16(bf[j_], af[i_], acc[i_][j_], 0, 0, 0);
    }
    __syncthreads();
  }

  // epilogue: lane holds m = tile_m + r, n = tile_n + q*4 + [0..4)
#pragma unroll
  for (int i_ = 0; i_ < MT; ++i_) {
    int m_g = m0 + wave_m * (MT * 16) + i_ * 16 + r;
#pragma unroll
    for (int j_ = 0; j_ < NT; ++j_) {
      int nb = n0 + wave_n * (NT * 16) + j_ * 16 + q * 4;
      f32x4 v = acc[i_][j_];
      f32x4 bb = *(const f32x4*)(biasp + nb);
      v += bb;
      if constexpr (MODE == 0) {
        union { u16 s[4]; uint2 d; } pk;
#pragma unroll
        for (int rg = 0; rg < 4; ++rg) pk.s[rg] = f2bf(gelu_f(v[rg]));
        *(uint2*)((u16*)Out + (size_t)m_g * HH + nb) = pk.d;
      } else if constexpr (MODE == 1) {
        int b = m_g >> 8, p = m_g & 255;
        *(f32x4*)((float*)Out + (size_t)(b * TT + 6 + p) * DD + nb) = v;
      } else if constexpr (MODE == 2) {
        union { u16 s[4]; uint2 d; } pk;
#pragma unroll
        for (int rg = 0; rg < 4; ++rg) pk.s[rg] = f2bf(gelu_f(v[rg]));
        *(uint2*)((u16*)Out + (size_t)(combo * 64 + m_g) * HH + nb) = pk.d;
      } else {
        int s = sel[cls_i * 64 + m_g];
        int j = combo & 1;
        float* dst = (float*)Out + (size_t)(m_g * TT + cls_i) * DD + nb;
        if (s == j) {
          *(f32x4*)dst = v;
        } else if (j == 0 && s == 2) {
          *(f32x4*)dst = (f32x4){0.f, 0.f, 0.f, 0.f};
        }
      }
    }
  }
}

// mega1: blocks [0,1536) patch layer1 (128x256); [1536,1824) cls layer1 (64x128)
__global__ __launch_bounds__(256, 2)
void mega1(const __hip_bfloat16* __restrict__ xb, const __hip_bfloat16* __restrict__ W1t,
           const float* __restrict__ b1, __hip_bfloat16* __restrict__ hid,
           const __hip_bfloat16* __restrict__ A1t, const float* __restrict__ A1b,
           __hip_bfloat16* __restrict__ hcls) {
  __shared__ __align__(16) char smem[(128 + 256) * 128];
  int bx = blockIdx.x;
  if (bx < 1536) gemm_body<128, 256, 0>(smem, bx, xb, W1t, b1, hid, nullptr);
  else           gemm_body<64, 128, 2>(smem, bx - 1536, xb, A1t, A1b, hcls, nullptr);
}

// mega2: blocks [0,768) patch layer2 (128x128); [768,840) cls layer2 (64x128, full K)
__global__ __launch_bounds__(256, 2)
void mega2(const __hip_bfloat16* __restrict__ hid, const __hip_bfloat16* __restrict__ W2t,
           const float* __restrict__ b2, float* __restrict__ out,
           const __hip_bfloat16* __restrict__ hcls, const __hip_bfloat16* __restrict__ A2t,
           const float* __restrict__ A2b, const int* __restrict__ sel) {
  __shared__ __align__(16) char smem[(128 + 128) * 128];
  int bx = blockIdx.x;
  if (bx < 768) gemm_body<128, 128, 1>(smem, bx, hid, W2t, b2, out, nullptr);
  else          gemm_body<64, 128, 3>(smem, bx - 768, hcls, A2t, A2b, out, sel);
}

extern "C" void kernel_launch(void* const* d_in, const int* in_sizes, int n_in,
                              void* d_out, int out_size, void* d_ws, size_t ws_size,
                              hipStream_t stream) {
  const float* x   = (const float*)d_in[0];
  const float* W1  = (const float*)d_in[1];
  const float* b1  = (const float*)d_in[2];
  const float* W2  = (const float*)d_in[3];
  const float* b2  = (const float*)d_in[4];
  const float* A1W = (const float*)d_in[5];
  const float* A1b = (const float*)d_in[6];
  const float* A2W = (const float*)d_in[7];
  const float* A2b = (const float*)d_in[8];
  const float* GW  = (const float*)d_in[9];
  float* out = (float*)d_out;

  char* ws = (char*)d_ws;
  __hip_bfloat16* xb   = (__hip_bfloat16*)(ws + 0);          // 25,755,648
  __hip_bfloat16* W1t  = (__hip_bfloat16*)(ws + 25755648);   //  4,718,592
  __hip_bfloat16* W2t  = (__hip_bfloat16*)(ws + 30474240);   //  4,718,592
  __hip_bfloat16* A1t  = (__hip_bfloat16*)(ws + 35192832);   // 23,592,960
  __hip_bfloat16* A2t  = (__hip_bfloat16*)(ws + 58785792);   // 23,592,960
  __hip_bfloat16* hcls = (__hip_bfloat16*)(ws + 82378752);   //  4,718,592
  int* sel             = (int*)(ws + 87097344);
  __hip_bfloat16* hid  = (__hip_bfloat16*)(ws + 87099136);   // 100,663,296

  wtrans<<<6912, 256, 0, stream>>>(W1, A1W, W2, A2W,
                                   (u16*)W1t, (u16*)A1t, (u16*)W2t, (u16*)A2t);
  castgate<<<6384, 256, 0, stream>>>(x, GW, (u16*)xb, sel);
  mega1<<<1824, 256, 0, stream>>>(xb, W1t, b1, hid, A1t, A1b, hcls);
  mega2<<<840, 256, 0, stream>>>(hid, W2t, b2, out, hcls, A2t, A2b, sel);
}